// Round 2
// baseline (4713.400 us; speedup 1.0000x reference)
//
#include <hip/hip_runtime.h>
#include <hip/hip_bf16.h>
#include <cstdint>
#include <cstddef>

// ---------------------------------------------------------------------------
// 2-layer GRU decoder. B=8192, H=512, ENC=1024, ATOM=64, 49 steps.
// 3 kernels/step: gru0_step, gru1_fused (merged dual GEMM), out_mfma.
// Gate-permuted weights: q = 48*(j/16) + 16*g + (j%16) <-> orig row g*512+j.
// Grid dim3(128,8): m-tile fastest-varying => XCD L2 locality on weights.
// R2: (a) K-loops rebuilt as counted-vmcnt double-buffer (raw s_barrier +
//     asm vmcnt(N), N = loads/tile, never 0 mid-loop) -- the R1 structure
//     drained vmcnt(0) every iter (__syncthreads), exposing full L2 latency
//     per K-step (profile: MfmaUtil 1.3%, stall-bound).
// (b) LDS bank-conflict swizzle: col16' = col16 ^ ((row>>1)&3) within each
//     16-row x 64B subtile. Applied on BOTH sides (rule 21): global source
//     column pre-swizzled per lane (gload_lds writes linearly), read offset
//     folds to a per-thread constant. 8-way -> 2-way (b128 floor).
// ---------------------------------------------------------------------------

typedef __attribute__((ext_vector_type(8))) __bf16 bf16x8;
typedef __attribute__((ext_vector_type(4))) __bf16 bf16x4;
typedef __attribute__((ext_vector_type(4))) float f32x4;

#define B_ROWS 8192
#define HID 512
#define GATE3 1536
#define ATOM 64
#define NSTEP 49

#define GLOAD_LDS16(gp, sp)                                                   \
  __builtin_amdgcn_global_load_lds(                                           \
      (__attribute__((address_space(1))) void*)(gp),                          \
      (__attribute__((address_space(3))) void*)(sp), 16, 0, 0)

__device__ inline float sig_(float x) { return 1.f / (1.f + __expf(-x)); }
__device__ inline float tanh_(float x) { return 2.f / (1.f + __expf(-2.f * x)) - 1.f; }

// ---------------------------------------------------------------------------
// K1: GRU0. gh0 = h0 @ whh0p^T; gi0 = G0p[p[row]] (b_ih0 folded);
// gate update -> h0_new (fp32 + bf16 mirror).
// Counted-vmcnt dbuf pipeline, swizzled LDS. 2x16KB LDS -> 5 blocks/CU.
// ---------------------------------------------------------------------------
__global__ __launch_bounds__(256) void gru0_step(
    const __bf16* __restrict__ h0b_c, const __bf16* __restrict__ whh0p,
    const float* __restrict__ G0p, const int* __restrict__ p,
    const float* __restrict__ bhh0p,
    const float* __restrict__ h0f_c, float* __restrict__ h0f_n,
    __bf16* __restrict__ h0b_n)
{
    __shared__ __bf16 As[2][64 * 32];    // 2 x 4 KB
    __shared__ __bf16 Bs[2][192 * 32];   // 2 x 12 KB

    const int tid = threadIdx.x, lane = tid & 63, w = tid >> 6;
    const int u = lane & 15, q = lane >> 4;
    const int m0 = blockIdx.x * 64;
    const int n0 = blockIdx.y * 192;
    const int t_ = blockIdx.y * 4 + w;
    const int j  = t_ * 16 + u;
    const int qb = t_ * 48 + u;
    // swizzle: within 16-row x 4-slot subtile, slot' = slot ^ ((row>>1)&3)
    const int k0   = (q ^ ((u >> 1) & 3)) * 8;              // read col (elems)
    const int scol = ((tid & 3) ^ ((tid >> 3) & 3)) * 8;    // stage col (elems)
    const int wo = w * 512;

    const __bf16* Ap  = h0b_c + (size_t)(m0 + (tid >> 2)) * HID + scol;
    const __bf16* Bg0 = whh0p + (size_t)(n0 + (tid >> 2)) * HID + scol;
    const __bf16* Bg1 = Bg0 + (size_t)64  * HID;
    const __bf16* Bg2 = Bg0 + (size_t)128 * HID;

    f32x4 acc[4][3] = {};

    // prologue: stage tile 0 into buf 0
    GLOAD_LDS16(Ap,  &As[0][wo]);
    GLOAD_LDS16(Bg0, &Bs[0][wo]);
    GLOAD_LDS16(Bg1, &Bs[0][2048 + wo]);
    GLOAD_LDS16(Bg2, &Bs[0][4096 + wo]);
    Ap += 32; Bg0 += 32; Bg1 += 32; Bg2 += 32;

    #pragma unroll
    for (int kt = 0; kt < 16; ++kt) {
        const int cur = kt & 1;
        if (kt < 15) {
            GLOAD_LDS16(Ap,  &As[cur ^ 1][wo]);
            GLOAD_LDS16(Bg0, &Bs[cur ^ 1][wo]);
            GLOAD_LDS16(Bg1, &Bs[cur ^ 1][2048 + wo]);
            GLOAD_LDS16(Bg2, &Bs[cur ^ 1][4096 + wo]);
            Ap += 32; Bg0 += 32; Bg1 += 32; Bg2 += 32;
            asm volatile("s_waitcnt vmcnt(4)" ::: "memory");  // tile kt arrived
        } else {
            asm volatile("s_waitcnt vmcnt(0)" ::: "memory");
        }
        __builtin_amdgcn_s_barrier();                         // buf[cur] ready

        bf16x8 af[4], bfr[3];
        #pragma unroll
        for (int mf = 0; mf < 4; ++mf)
            af[mf] = *(const bf16x8*)&As[cur][(mf * 16 + u) * 32 + k0];
        #pragma unroll
        for (int g = 0; g < 3; ++g)
            bfr[g] = *(const bf16x8*)&Bs[cur][(w * 48 + g * 16 + u) * 32 + k0];
        #pragma unroll
        for (int mf = 0; mf < 4; ++mf)
            #pragma unroll
            for (int g = 0; g < 3; ++g)
                acc[mf][g] = __builtin_amdgcn_mfma_f32_16x16x32_bf16(
                    af[mf], bfr[g], acc[mf][g], 0, 0, 0);

        asm volatile("s_waitcnt lgkmcnt(0)" ::: "memory");    // my reads done
        __builtin_amdgcn_s_barrier();                         // all reads done
    }

    const float bhr = bhh0p[qb], bhz = bhh0p[qb + 16], bhn = bhh0p[qb + 32];
    const int rbase = m0 + (q << 2);
    #pragma unroll
    for (int mf = 0; mf < 4; ++mf)
        #pragma unroll
        for (int r = 0; r < 4; ++r) {
            const int row = rbase + mf * 16 + r;
            const float* g0 = G0p + (size_t)p[row] * GATE3 + qb;
            const float rr = sig_(g0[0]  + acc[mf][0][r] + bhr);
            const float zz = sig_(g0[16] + acc[mf][1][r] + bhz);
            const float nn = tanh_(g0[32] + rr * (acc[mf][2][r] + bhn));
            const float hp = h0f_c[(size_t)row * HID + j];
            const float hv = (1.f - zz) * nn + zz * hp;
            h0f_n[(size_t)row * HID + j] = hv;
            h0b_n[(size_t)row * HID + j] = (__bf16)hv;
        }
}

// ---------------------------------------------------------------------------
// K2: GRU1 fused. gi1 = h0_new @ wih1p^T AND gh1 = h1 @ whh1p^T in ONE
// counted-vmcnt dbuf K-loop (8 loads/tile in flight, 24 MFMA/phase).
// LDS 64KB -> 2 blocks/CU; in-block pipeline carries the latency hiding.
// ---------------------------------------------------------------------------
__global__ __launch_bounds__(256) void gru1_fused(
    const __bf16* __restrict__ h0b_n, const __bf16* __restrict__ wih1p,
    const __bf16* __restrict__ h1b_c, const __bf16* __restrict__ whh1p,
    const float* __restrict__ bih1p, const float* __restrict__ bhh1p,
    const float* __restrict__ h1f_c, float* __restrict__ h1f_n,
    __bf16* __restrict__ h1b_n)
{
    __shared__ __bf16 Asi[2][64 * 32];
    __shared__ __bf16 Ash[2][64 * 32];
    __shared__ __bf16 Bsi[2][192 * 32];
    __shared__ __bf16 Bsh[2][192 * 32];

    const int tid = threadIdx.x, lane = tid & 63, w = tid >> 6;
    const int u = lane & 15, q = lane >> 4;
    const int m0 = blockIdx.x * 64;
    const int n0 = blockIdx.y * 192;
    const int t_ = blockIdx.y * 4 + w;
    const int j  = t_ * 16 + u;
    const int qb = t_ * 48 + u;
    const int k0   = (q ^ ((u >> 1) & 3)) * 8;
    const int scol = ((tid & 3) ^ ((tid >> 3) & 3)) * 8;
    const int wo = w * 512;

    const __bf16* Api = h0b_n + (size_t)(m0 + (tid >> 2)) * HID + scol;
    const __bf16* Aph = h1b_c + (size_t)(m0 + (tid >> 2)) * HID + scol;
    const __bf16* Bi0 = wih1p + (size_t)(n0 + (tid >> 2)) * HID + scol;
    const __bf16* Bh0 = whh1p + (size_t)(n0 + (tid >> 2)) * HID + scol;
    const __bf16* Bi1 = Bi0 + (size_t)64  * HID;
    const __bf16* Bi2 = Bi0 + (size_t)128 * HID;
    const __bf16* Bh1 = Bh0 + (size_t)64  * HID;
    const __bf16* Bh2 = Bh0 + (size_t)128 * HID;

    f32x4 acc_i[4][3] = {};
    f32x4 acc_h[4][3] = {};

    GLOAD_LDS16(Api, &Asi[0][wo]);
    GLOAD_LDS16(Aph, &Ash[0][wo]);
    GLOAD_LDS16(Bi0, &Bsi[0][wo]);
    GLOAD_LDS16(Bi1, &Bsi[0][2048 + wo]);
    GLOAD_LDS16(Bi2, &Bsi[0][4096 + wo]);
    GLOAD_LDS16(Bh0, &Bsh[0][wo]);
    GLOAD_LDS16(Bh1, &Bsh[0][2048 + wo]);
    GLOAD_LDS16(Bh2, &Bsh[0][4096 + wo]);
    Api += 32; Aph += 32;
    Bi0 += 32; Bi1 += 32; Bi2 += 32;
    Bh0 += 32; Bh1 += 32; Bh2 += 32;

    #pragma unroll
    for (int kt = 0; kt < 16; ++kt) {
        const int cur = kt & 1;
        if (kt < 15) {
            GLOAD_LDS16(Api, &Asi[cur ^ 1][wo]);
            GLOAD_LDS16(Aph, &Ash[cur ^ 1][wo]);
            GLOAD_LDS16(Bi0, &Bsi[cur ^ 1][wo]);
            GLOAD_LDS16(Bi1, &Bsi[cur ^ 1][2048 + wo]);
            GLOAD_LDS16(Bi2, &Bsi[cur ^ 1][4096 + wo]);
            GLOAD_LDS16(Bh0, &Bsh[cur ^ 1][wo]);
            GLOAD_LDS16(Bh1, &Bsh[cur ^ 1][2048 + wo]);
            GLOAD_LDS16(Bh2, &Bsh[cur ^ 1][4096 + wo]);
            Api += 32; Aph += 32;
            Bi0 += 32; Bi1 += 32; Bi2 += 32;
            Bh0 += 32; Bh1 += 32; Bh2 += 32;
            asm volatile("s_waitcnt vmcnt(8)" ::: "memory");
        } else {
            asm volatile("s_waitcnt vmcnt(0)" ::: "memory");
        }
        __builtin_amdgcn_s_barrier();

        bf16x8 bfi[3], bfh[3];
        #pragma unroll
        for (int g = 0; g < 3; ++g) {
            bfi[g] = *(const bf16x8*)&Bsi[cur][(w * 48 + g * 16 + u) * 32 + k0];
            bfh[g] = *(const bf16x8*)&Bsh[cur][(w * 48 + g * 16 + u) * 32 + k0];
        }
        #pragma unroll
        for (int mf = 0; mf < 4; ++mf) {
            const bf16x8 afi = *(const bf16x8*)&Asi[cur][(mf * 16 + u) * 32 + k0];
            #pragma unroll
            for (int g = 0; g < 3; ++g)
                acc_i[mf][g] = __builtin_amdgcn_mfma_f32_16x16x32_bf16(
                    afi, bfi[g], acc_i[mf][g], 0, 0, 0);
            const bf16x8 afh = *(const bf16x8*)&Ash[cur][(mf * 16 + u) * 32 + k0];
            #pragma unroll
            for (int g = 0; g < 3; ++g)
                acc_h[mf][g] = __builtin_amdgcn_mfma_f32_16x16x32_bf16(
                    afh, bfh[g], acc_h[mf][g], 0, 0, 0);
        }

        asm volatile("s_waitcnt lgkmcnt(0)" ::: "memory");
        __builtin_amdgcn_s_barrier();
    }

    const float bir = bih1p[qb], biz = bih1p[qb + 16], bin = bih1p[qb + 32];
    const float bhr = bhh1p[qb], bhz = bhh1p[qb + 16], bhn = bhh1p[qb + 32];
    const int rbase = m0 + (q << 2);
    #pragma unroll
    for (int mf = 0; mf < 4; ++mf)
        #pragma unroll
        for (int r = 0; r < 4; ++r) {
            const int row = rbase + mf * 16 + r;
            const float rr = sig_(acc_i[mf][0][r] + bir + acc_h[mf][0][r] + bhr);
            const float zz = sig_(acc_i[mf][1][r] + biz + acc_h[mf][1][r] + bhz);
            const float nn = tanh_(acc_i[mf][2][r] + bin +
                                   rr * (acc_h[mf][2][r] + bhn));
            const float hp = h1f_c[(size_t)row * HID + j];
            const float hv = (1.f - zz) * nn + zz * hp;
            h1f_n[(size_t)row * HID + j] = hv;
            h1b_n[(size_t)row * HID + j] = (__bf16)hv;
        }
}

// ---------------------------------------------------------------------------
// K3: logits = h1_new @ w_out^T + b_out (BM=32, N=64, K=512); log_softmax +
// argmax fused. 256 blocks x 128 threads. Counted-vmcnt dbuf (the R1 version
// used __syncthreads, whose implicit vmcnt(0) drained the prefetch).
// ---------------------------------------------------------------------------
__global__ __launch_bounds__(128) void out_mfma(
    const __bf16* __restrict__ h1b, const __bf16* __restrict__ woutb,
    const float* __restrict__ bout, float* __restrict__ y, int* __restrict__ p)
{
    __shared__ __bf16 As[2][32 * 32];   // 2 x 2 KB
    __shared__ __bf16 Bs[2][64 * 32];   // 2 x 4 KB

    const int tid  = threadIdx.x;
    const int lane = tid & 63;
    const int w    = tid >> 6;            // 0..1
    const int m0   = blockIdx.x * 32;
    const int u    = lane & 15, q = lane >> 4;
    const int k0   = (q ^ ((u >> 1) & 3)) * 8;
    const int scol = ((tid & 3) ^ ((tid >> 3) & 3)) * 8;
    const int wo   = w * 512;

    f32x4 acc[4] = {};

    const __bf16* Ap  = h1b   + (size_t)(m0 + (tid >> 2)) * HID + scol;
    const __bf16* Wp0 = woutb + (size_t)(tid >> 2) * HID + scol;
    const __bf16* Wp1 = Wp0 + (size_t)32 * HID;

    GLOAD_LDS16(Ap,  &As[0][wo]);
    GLOAD_LDS16(Wp0, &Bs[0][wo]);
    GLOAD_LDS16(Wp1, &Bs[0][1024 + wo]);
    Ap += 32; Wp0 += 32; Wp1 += 32;

    #pragma unroll
    for (int kt = 0; kt < 16; ++kt) {
        const int cur = kt & 1;
        if (kt < 15) {
            GLOAD_LDS16(Ap,  &As[cur ^ 1][wo]);
            GLOAD_LDS16(Wp0, &Bs[cur ^ 1][wo]);
            GLOAD_LDS16(Wp1, &Bs[cur ^ 1][1024 + wo]);
            Ap += 32; Wp0 += 32; Wp1 += 32;
            asm volatile("s_waitcnt vmcnt(3)" ::: "memory");
        } else {
            asm volatile("s_waitcnt vmcnt(0)" ::: "memory");
        }
        __builtin_amdgcn_s_barrier();

        const bf16x8 af = *(const bf16x8*)&As[cur][(w * 16 + u) * 32 + k0];
        #pragma unroll
        for (int nf = 0; nf < 4; ++nf) {
            const bf16x8 bfr = *(const bf16x8*)&Bs[cur][(nf * 16 + u) * 32 + k0];
            acc[nf] = __builtin_amdgcn_mfma_f32_16x16x32_bf16(af, bfr, acc[nf], 0, 0, 0);
        }

        asm volatile("s_waitcnt lgkmcnt(0)" ::: "memory");
        __builtin_amdgcn_s_barrier();
    }

    #pragma unroll
    for (int r = 0; r < 4; ++r) {
        const int row = m0 + w * 16 + (q << 2) + r;
        float l[4];
        #pragma unroll
        for (int nf = 0; nf < 4; ++nf) l[nf] = acc[nf][r] + bout[nf * 16 + u];

        float mv = l[0]; int mi = u;
        #pragma unroll
        for (int nf = 1; nf < 4; ++nf)
            if (l[nf] > mv) { mv = l[nf]; mi = nf * 16 + u; }
        #pragma unroll
        for (int off = 1; off <= 8; off <<= 1) {
            const float ov = __shfl_xor(mv, off, 64);
            const int   oi = __shfl_xor(mi, off, 64);
            if (ov > mv || (ov == mv && oi < mi)) { mv = ov; mi = oi; }
        }
        float se = 0.f;
        #pragma unroll
        for (int nf = 0; nf < 4; ++nf) se += __expf(l[nf] - mv);
        #pragma unroll
        for (int off = 1; off <= 8; off <<= 1) se += __shfl_xor(se, off, 64);
        const float lse = logf(se);

        #pragma unroll
        for (int nf = 0; nf < 4; ++nf)
            y[(size_t)row * ATOM + nf * 16 + u] = l[nf] - mv - lse;
        if (u == 0) p[row] = mi;
    }
}

// ---------------------------------------------------------------------------
// Init GEMM (enc -> h): 128x128 tile, LDS-staged, tanh epilogue split h0|h1.
// Runs once; left in the simple 2-barrier form.
// ---------------------------------------------------------------------------
__global__ __launch_bounds__(256) void gemm_init(
    const __bf16* __restrict__ A, const __bf16* __restrict__ B,
    int N, int K, const float* __restrict__ bias,
    float* __restrict__ H0f, __bf16* __restrict__ H0b,
    float* __restrict__ H1f, __bf16* __restrict__ H1b)
{
    __shared__ __bf16 As[128 * 32];
    __shared__ __bf16 Bs[128 * 32];

    const int tid  = threadIdx.x;
    const int lane = tid & 63;
    const int w    = tid >> 6;
    const int wm   = w >> 1, wn = w & 1;
    const int m0   = blockIdx.x * 128;
    const int n0   = blockIdx.y * 128;

    f32x4 acc[4][4] = {};

    const int i0 = w * 64 + lane;
    const int i1 = i0 + 256;
    const __bf16* Ap0 = A + (size_t)(m0 + (i0 >> 2)) * K + (i0 & 3) * 8;
    const __bf16* Ap1 = A + (size_t)(m0 + (i1 >> 2)) * K + (i1 & 3) * 8;
    const __bf16* Bp0 = B + (size_t)(n0 + (i0 >> 2)) * K + (i0 & 3) * 8;
    const __bf16* Bp1 = B + (size_t)(n0 + (i1 >> 2)) * K + (i1 & 3) * 8;
    __bf16* As0 = As + w * 512;
    __bf16* As1 = As + 2048 + w * 512;
    __bf16* Bs0 = Bs + w * 512;
    __bf16* Bs1 = Bs + 2048 + w * 512;

    const int mrow = wm * 64 + (lane & 15);
    const int nrow = wn * 64 + (lane & 15);
    const int koff = (lane >> 4) * 8;

    for (int kt = 0; kt < K / 32; ++kt) {
        __syncthreads();
        GLOAD_LDS16(Ap0, As0);
        GLOAD_LDS16(Ap1, As1);
        GLOAD_LDS16(Bp0, Bs0);
        GLOAD_LDS16(Bp1, Bs1);
        Ap0 += 32; Ap1 += 32; Bp0 += 32; Bp1 += 32;
        __syncthreads();

        bf16x8 af[4], bfr[4];
        #pragma unroll
        for (int f = 0; f < 4; ++f) {
            af[f]  = *(const bf16x8*)&As[(mrow + f * 16) * 32 + koff];
            bfr[f] = *(const bf16x8*)&Bs[(nrow + f * 16) * 32 + koff];
        }
        #pragma unroll
        for (int mf = 0; mf < 4; ++mf)
            #pragma unroll
            for (int nf = 0; nf < 4; ++nf)
                acc[mf][nf] = __builtin_amdgcn_mfma_f32_16x16x32_bf16(
                    af[mf], bfr[nf], acc[mf][nf], 0, 0, 0);
    }

    const int colb = n0 + wn * 64 + (lane & 15);
    const int rowb = m0 + wm * 64 + ((lane >> 4) << 2);
    #pragma unroll
    for (int mf = 0; mf < 4; ++mf)
        #pragma unroll
        for (int nf = 0; nf < 4; ++nf) {
            const int col = colb + nf * 16;
            #pragma unroll
            for (int r = 0; r < 4; ++r) {
                const int row = rowb + mf * 16 + r;
                const float v = tanhf(acc[mf][nf][r] + bias[col]);
                if (col < HID) {
                    H0f[(size_t)row * HID + col] = v;
                    H0b[(size_t)row * HID + col] = (__bf16)v;
                } else {
                    H1f[(size_t)row * HID + col - HID] = v;
                    H1b[(size_t)row * HID + col - HID] = (__bf16)v;
                }
            }
        }
}

// ---------------------------------------------------------------------------
// prep kernels
// ---------------------------------------------------------------------------
__device__ inline int permQ(int q) {          // permuted q -> original row
    const int t = q / 48, rem = q % 48;
    return (rem / 16) * HID + t * 16 + (rem % 16);
}

__global__ __launch_bounds__(256) void f2b(const float* __restrict__ s,
                                           __bf16* __restrict__ d, int n)
{
    const int i = (blockIdx.x * 256 + threadIdx.x) * 4;
    if (i + 3 < n) {
        const float4 v = *(const float4*)(s + i);
        bf16x4 o = { (__bf16)v.x, (__bf16)v.y, (__bf16)v.z, (__bf16)v.w };
        *(bf16x4*)(d + i) = o;
    }
}

__global__ __launch_bounds__(256) void f2bp(const float* __restrict__ s,
                                            __bf16* __restrict__ d)
{
    const int idx = blockIdx.x * 256 + threadIdx.x;   // 1536*128
    const int q = idx >> 7, k = (idx & 127) << 2;
    const int o = permQ(q);
    const float4 v = *(const float4*)(s + (size_t)o * HID + k);
    bf16x4 ov = { (__bf16)v.x, (__bf16)v.y, (__bf16)v.z, (__bf16)v.w };
    *(bf16x4*)(d + (size_t)q * HID + k) = ov;
}

__global__ __launch_bounds__(256) void bperm(const float* __restrict__ s,
                                             float* __restrict__ d)
{
    const int q = blockIdx.x * 256 + threadIdx.x;
    if (q < GATE3) d[q] = s[permQ(q)];
}

__global__ __launch_bounds__(256) void g0pk(const float* __restrict__ emb,
                                            const float* __restrict__ wih0,
                                            const float* __restrict__ bih0,
                                            float* __restrict__ G0p)
{
    const int i = blockIdx.x * 256 + threadIdx.x;   // 64*1536
    if (i >= ATOM * GATE3) return;
    const int a = i / GATE3, q = i % GATE3;
    const int o = permQ(q);
    float s = bih0[o];
    for (int k = 0; k < 50; ++k) s += emb[a * 50 + k] * wih0[o * 50 + k];
    G0p[i] = s;
}

__global__ __launch_bounds__(256) void initp(int* __restrict__ p)
{
    const int i = blockIdx.x * 256 + threadIdx.x;
    if (i < B_ROWS) p[i] = 1;   // SOS
}

// ---------------------------------------------------------------------------
extern "C" void kernel_launch(void* const* d_in, const int* in_sizes, int n_in,
                              void* d_out, int out_size, void* d_ws, size_t ws_size,
                              hipStream_t stream)
{
    (void)in_sizes; (void)n_in; (void)out_size; (void)ws_size;
    const float* enc   = (const float*)d_in[0];
    const float* emb   = (const float*)d_in[1];
    const float* w_h0  = (const float*)d_in[2];
    const float* b_h0  = (const float*)d_in[3];
    const float* w_ih0 = (const float*)d_in[4];
    const float* w_hh0 = (const float*)d_in[5];
    const float* b_ih0 = (const float*)d_in[6];
    const float* b_hh0 = (const float*)d_in[7];
    const float* w_ih1 = (const float*)d_in[8];
    const float* w_hh1 = (const float*)d_in[9];
    const float* b_ih1 = (const float*)d_in[10];
    const float* b_hh1 = (const float*)d_in[11];
    const float* w_out = (const float*)d_in[12];
    const float* b_out = (const float*)d_in[13];
    float* out = (float*)d_out;

    char* ws = (char*)d_ws;
    size_t off = 0;
    auto alloc = [&](size_t bytes) -> void* {
        void* pp = ws + off;
        off = (off + bytes + 255) & ~(size_t)255;
        return pp;
    };
    __bf16* whh0p = (__bf16*)alloc((size_t)GATE3 * HID * 2);
    __bf16* wih1p = (__bf16*)alloc((size_t)GATE3 * HID * 2);
    __bf16* whh1p = (__bf16*)alloc((size_t)GATE3 * HID * 2);
    __bf16* woutb = (__bf16*)alloc((size_t)ATOM * HID * 2);
    float*  G0p   = (float*) alloc((size_t)ATOM * GATE3 * 4);
    float*  bhh0p = (float*) alloc(GATE3 * 4);
    float*  bih1p = (float*) alloc(GATE3 * 4);
    float*  bhh1p = (float*) alloc(GATE3 * 4);
    float*  h0f[2]; __bf16* h0b[2]; float* h1f[2]; __bf16* h1b[2];
    for (int i = 0; i < 2; ++i) {
        h0f[i] = (float*) alloc((size_t)B_ROWS * HID * 4);
        h0b[i] = (__bf16*)alloc((size_t)B_ROWS * HID * 2);
        h1f[i] = (float*) alloc((size_t)B_ROWS * HID * 4);
        h1b[i] = (__bf16*)alloc((size_t)B_ROWS * HID * 2);
    }
    int* p = (int*)alloc((size_t)B_ROWS * 4);
    __bf16* enc_b = (__bf16*)alloc((size_t)B_ROWS * 1024 * 2);
    __bf16* wh0b  = (__bf16*)alloc((size_t)1024 * 1024 * 2);

    // ---- prep ----
    f2b <<<8192, 256, 0, stream>>>(enc,  enc_b, B_ROWS * 1024);
    f2b <<<1024, 256, 0, stream>>>(w_h0, wh0b,  1024 * 1024);
    f2b <<<32,   256, 0, stream>>>(w_out, woutb, ATOM * HID);
    f2bp<<<768,  256, 0, stream>>>(w_hh0, whh0p);
    f2bp<<<768,  256, 0, stream>>>(w_ih1, wih1p);
    f2bp<<<768,  256, 0, stream>>>(w_hh1, whh1p);
    bperm<<<6, 256, 0, stream>>>(b_hh0, bhh0p);
    bperm<<<6, 256, 0, stream>>>(b_ih1, bih1p);
    bperm<<<6, 256, 0, stream>>>(b_hh1, bhh1p);
    g0pk<<<384, 256, 0, stream>>>(emb, w_ih0, b_ih0, G0p);
    initp<<<32, 256, 0, stream>>>(p);

    gemm_init<<<dim3(B_ROWS / 128, 1024 / 128), 256, 0, stream>>>(
        enc_b, wh0b, 1024, 1024, b_h0, h0f[0], h0b[0], h1f[0], h1b[0]);

    // ---- 49 decode steps: 3 launches each ----
    const dim3 gGrid(B_ROWS / 64, GATE3 / 192);   // m-tile fastest (XCD locality)
    for (int step = 0; step < NSTEP; ++step) {
        const int cur = step & 1, nxt = cur ^ 1;
        gru0_step<<<gGrid, 256, 0, stream>>>(
            h0b[cur], whh0p, G0p, p, bhh0p, h0f[cur], h0f[nxt], h0b[nxt]);
        gru1_fused<<<gGrid, 256, 0, stream>>>(
            h0b[nxt], wih1p, h1b[cur], whh1p, bih1p, bhh1p,
            h1f[cur], h1f[nxt], h1b[nxt]);
        out_mfma<<<B_ROWS / 32, 128, 0, stream>>>(
            h1b[nxt], woutb, b_out, out + (size_t)step * B_ROWS * ATOM, p);
    }
}

// Round 4
// 3832.070 us; speedup vs baseline: 1.2300x; 1.2300x over previous
//
#include <hip/hip_runtime.h>
#include <hip/hip_bf16.h>
#include <cstdint>
#include <cstddef>

// ---------------------------------------------------------------------------
// 2-layer GRU decoder. B=8192, H=512, ENC=1024, ATOM=64, 49 steps.
// 3 kernels/step: gru0_step, gru1_fused (merged dual GEMM), out_mfma.
// Gate-permuted weights: q = 48*(j/16) + 16*g + (j%16) <-> orig row g*512+j.
// Grid dim3(128,8): m-tile fastest-varying => XCD L2 locality on weights.
// R3: weights in MFMA B-FRAGMENT layout in global memory, loaded straight
//     to VGPRs as coalesced 1KB wave-loads (B never shared between waves;
//     LDS staging of B was pure overhead). A stays LDS-staged (4-way wave
//     sharing) with swizzle (bank conflicts measured 0) + counted-vmcnt dbuf.
// R4 FIX: R3 raced -- ordinary B-frag loads and the prologue's
//     global_load_lds share one unfenced window, so the compiler could
//     issue the A-stage DMA late and vmcnt(4) completed with it in flight
//     (stale LDS on the first K-tile). Fix: sched_barrier(0) + asm memory
//     fence after the prologue, and iter-0 waits vmcnt(0) (full drain,
//     once per kernel). Steady-state groups are fence-separated => counted
//     waits (4/8/5) remain exact.
// Frag layout for a [R][512] bf16 matrix read as MFMA A/B operand:
//     elem(r,k) -> ((r>>4)*16 + (k>>5))*512 + ((k>>3)&3)*128 + (r&15)*8 + (k&7)
//     => frag (fr,kt) is a contiguous 1KB block, lane l reads l*16B.
// ---------------------------------------------------------------------------

typedef __attribute__((ext_vector_type(8))) __bf16 bf16x8;
typedef __attribute__((ext_vector_type(4))) __bf16 bf16x4;
typedef __attribute__((ext_vector_type(4))) float f32x4;

#define B_ROWS 8192
#define HID 512
#define GATE3 1536
#define ATOM 64
#define NSTEP 49

#define GLOAD_LDS16(gp, sp)                                                   \
  __builtin_amdgcn_global_load_lds(                                           \
      (__attribute__((address_space(1))) void*)(gp),                          \
      (__attribute__((address_space(3))) void*)(sp), 16, 0, 0)

#define PROLOGUE_FENCE()                                                      \
  do {                                                                        \
    __builtin_amdgcn_sched_barrier(0);                                        \
    asm volatile("" ::: "memory");                                            \
  } while (0)

__device__ inline float sig_(float x) { return 1.f / (1.f + __expf(-x)); }
__device__ inline float tanh_(float x) { return 2.f / (1.f + __expf(-2.f * x)) - 1.f; }

// ---------------------------------------------------------------------------
// K1: GRU0. gh0 = h0 @ whh0f^T; gi0 = G0p[p[row]] (b_ih0 folded);
// gate update -> h0_new (fp32 + bf16 mirror).
// A: LDS dbuf (8KB) + swizzle. B: reg-frags from frag-layout global.
// Per iter: 1 gload_lds + 3 B-loads -> vmcnt(4) (iter 0: vmcnt(0)).
// ---------------------------------------------------------------------------
__global__ __launch_bounds__(256) void gru0_step(
    const __bf16* __restrict__ h0b_c, const __bf16* __restrict__ whh0f,
    const float* __restrict__ G0p, const int* __restrict__ p,
    const float* __restrict__ bhh0p,
    const float* __restrict__ h0f_c, float* __restrict__ h0f_n,
    __bf16* __restrict__ h0b_n)
{
    __shared__ __bf16 As[2][64 * 32];    // 2 x 4 KB

    const int tid = threadIdx.x, lane = tid & 63, w = tid >> 6;
    const int u = lane & 15, q = lane >> 4;
    const int m0 = blockIdx.x * 64;
    const int t_ = blockIdx.y * 4 + w;
    const int j  = t_ * 16 + u;
    const int qb = t_ * 48 + u;
    const int k0   = (q ^ ((u >> 1) & 3)) * 8;              // A read col
    const int scol = ((tid & 3) ^ ((tid >> 3) & 3)) * 8;    // A stage col
    const int wo = w * 512;

    const __bf16* Ap = h0b_c + (size_t)(m0 + (tid >> 2)) * HID + scol;
    // B frag (g, kt) at Bf + (g*16 + kt)*512  (fr = t_*3 + g)
    const __bf16* Bf = whh0f + (size_t)(t_ * 48) * 512 + lane * 8;
    #define BFR0(g, kt) (*(const bf16x8*)(Bf + (size_t)((g) * 16 + (kt)) * 512))

    f32x4 acc[4][3] = {};
    bf16x8 bfr[2][3];

    GLOAD_LDS16(Ap, &As[0][wo]); Ap += 32;
    bfr[0][0] = BFR0(0, 0);
    bfr[0][1] = BFR0(1, 0);
    bfr[0][2] = BFR0(2, 0);
    PROLOGUE_FENCE();

    #pragma unroll
    for (int kt = 0; kt < 16; ++kt) {
        const int cur = kt & 1;
        if (kt < 15) {
            GLOAD_LDS16(Ap, &As[cur ^ 1][wo]); Ap += 32;
            bfr[cur ^ 1][0] = BFR0(0, kt + 1);
            bfr[cur ^ 1][1] = BFR0(1, kt + 1);
            bfr[cur ^ 1][2] = BFR0(2, kt + 1);
            if (kt == 0) asm volatile("s_waitcnt vmcnt(0)" ::: "memory");
            else         asm volatile("s_waitcnt vmcnt(4)" ::: "memory");
        } else {
            asm volatile("s_waitcnt vmcnt(0)" ::: "memory");
        }
        __builtin_amdgcn_s_barrier();                         // As[cur] ready

        bf16x8 af[4];
        #pragma unroll
        for (int mf = 0; mf < 4; ++mf)
            af[mf] = *(const bf16x8*)&As[cur][(mf * 16 + u) * 32 + k0];
        #pragma unroll
        for (int mf = 0; mf < 4; ++mf)
            #pragma unroll
            for (int g = 0; g < 3; ++g)
                acc[mf][g] = __builtin_amdgcn_mfma_f32_16x16x32_bf16(
                    af[mf], bfr[cur][g], acc[mf][g], 0, 0, 0);

        asm volatile("s_waitcnt lgkmcnt(0)" ::: "memory");
        __builtin_amdgcn_s_barrier();
    }

    const float bhr = bhh0p[qb], bhz = bhh0p[qb + 16], bhn = bhh0p[qb + 32];
    const int rbase = m0 + (q << 2);
    #pragma unroll
    for (int mf = 0; mf < 4; ++mf)
        #pragma unroll
        for (int r = 0; r < 4; ++r) {
            const int row = rbase + mf * 16 + r;
            const float* g0 = G0p + (size_t)p[row] * GATE3 + qb;
            const float rr = sig_(g0[0]  + acc[mf][0][r] + bhr);
            const float zz = sig_(g0[16] + acc[mf][1][r] + bhz);
            const float nn = tanh_(g0[32] + rr * (acc[mf][2][r] + bhn));
            const float hp = h0f_c[(size_t)row * HID + j];
            const float hv = (1.f - zz) * nn + zz * hp;
            h0f_n[(size_t)row * HID + j] = hv;
            h0b_n[(size_t)row * HID + j] = (__bf16)hv;
        }
}

// ---------------------------------------------------------------------------
// K2: GRU1 fused. gi1 = h0_new @ wih1f^T AND gh1 = h1 @ whh1f^T in one
// K-loop. A(x2): LDS dbuf (16KB) + swizzle. B(x2): reg-frags from global.
// Per iter: 2 gload_lds + 6 B-loads -> vmcnt(8) (iter 0: vmcnt(0)).
// ---------------------------------------------------------------------------
__global__ __launch_bounds__(256) void gru1_fused(
    const __bf16* __restrict__ h0b_n, const __bf16* __restrict__ wih1f,
    const __bf16* __restrict__ h1b_c, const __bf16* __restrict__ whh1f,
    const float* __restrict__ bih1p, const float* __restrict__ bhh1p,
    const float* __restrict__ h1f_c, float* __restrict__ h1f_n,
    __bf16* __restrict__ h1b_n)
{
    __shared__ __bf16 Asi[2][64 * 32];   // 2 x 4 KB
    __shared__ __bf16 Ash[2][64 * 32];   // 2 x 4 KB

    const int tid = threadIdx.x, lane = tid & 63, w = tid >> 6;
    const int u = lane & 15, q = lane >> 4;
    const int m0 = blockIdx.x * 64;
    const int t_ = blockIdx.y * 4 + w;
    const int j  = t_ * 16 + u;
    const int qb = t_ * 48 + u;
    const int k0   = (q ^ ((u >> 1) & 3)) * 8;
    const int scol = ((tid & 3) ^ ((tid >> 3) & 3)) * 8;
    const int wo = w * 512;

    const __bf16* Api = h0b_n + (size_t)(m0 + (tid >> 2)) * HID + scol;
    const __bf16* Aph = h1b_c + (size_t)(m0 + (tid >> 2)) * HID + scol;
    const __bf16* Bfi = wih1f + (size_t)(t_ * 48) * 512 + lane * 8;
    const __bf16* Bfh = whh1f + (size_t)(t_ * 48) * 512 + lane * 8;
    #define BFRI(g, kt) (*(const bf16x8*)(Bfi + (size_t)((g) * 16 + (kt)) * 512))
    #define BFRH(g, kt) (*(const bf16x8*)(Bfh + (size_t)((g) * 16 + (kt)) * 512))

    f32x4 acc_i[4][3] = {};
    f32x4 acc_h[4][3] = {};
    bf16x8 bfi[2][3], bfh[2][3];

    GLOAD_LDS16(Api, &Asi[0][wo]); Api += 32;
    GLOAD_LDS16(Aph, &Ash[0][wo]); Aph += 32;
    #pragma unroll
    for (int g = 0; g < 3; ++g) {
        bfi[0][g] = BFRI(g, 0);
        bfh[0][g] = BFRH(g, 0);
    }
    PROLOGUE_FENCE();

    #pragma unroll
    for (int kt = 0; kt < 16; ++kt) {
        const int cur = kt & 1;
        if (kt < 15) {
            GLOAD_LDS16(Api, &Asi[cur ^ 1][wo]); Api += 32;
            GLOAD_LDS16(Aph, &Ash[cur ^ 1][wo]); Aph += 32;
            #pragma unroll
            for (int g = 0; g < 3; ++g) {
                bfi[cur ^ 1][g] = BFRI(g, kt + 1);
                bfh[cur ^ 1][g] = BFRH(g, kt + 1);
            }
            if (kt == 0) asm volatile("s_waitcnt vmcnt(0)" ::: "memory");
            else         asm volatile("s_waitcnt vmcnt(8)" ::: "memory");
        } else {
            asm volatile("s_waitcnt vmcnt(0)" ::: "memory");
        }
        __builtin_amdgcn_s_barrier();

        #pragma unroll
        for (int mf = 0; mf < 4; ++mf) {
            const bf16x8 afi = *(const bf16x8*)&Asi[cur][(mf * 16 + u) * 32 + k0];
            #pragma unroll
            for (int g = 0; g < 3; ++g)
                acc_i[mf][g] = __builtin_amdgcn_mfma_f32_16x16x32_bf16(
                    afi, bfi[cur][g], acc_i[mf][g], 0, 0, 0);
            const bf16x8 afh = *(const bf16x8*)&Ash[cur][(mf * 16 + u) * 32 + k0];
            #pragma unroll
            for (int g = 0; g < 3; ++g)
                acc_h[mf][g] = __builtin_amdgcn_mfma_f32_16x16x32_bf16(
                    afh, bfh[cur][g], acc_h[mf][g], 0, 0, 0);
        }

        asm volatile("s_waitcnt lgkmcnt(0)" ::: "memory");
        __builtin_amdgcn_s_barrier();
    }

    const float bir = bih1p[qb], biz = bih1p[qb + 16], bin = bih1p[qb + 32];
    const float bhr = bhh1p[qb], bhz = bhh1p[qb + 16], bhn = bhh1p[qb + 32];
    const int rbase = m0 + (q << 2);
    #pragma unroll
    for (int mf = 0; mf < 4; ++mf)
        #pragma unroll
        for (int r = 0; r < 4; ++r) {
            const int row = rbase + mf * 16 + r;
            const float rr = sig_(acc_i[mf][0][r] + bir + acc_h[mf][0][r] + bhr);
            const float zz = sig_(acc_i[mf][1][r] + biz + acc_h[mf][1][r] + bhz);
            const float nn = tanh_(acc_i[mf][2][r] + bin +
                                   rr * (acc_h[mf][2][r] + bhn));
            const float hp = h1f_c[(size_t)row * HID + j];
            const float hv = (1.f - zz) * nn + zz * hp;
            h1f_n[(size_t)row * HID + j] = hv;
            h1b_n[(size_t)row * HID + j] = (__bf16)hv;
        }
}

// ---------------------------------------------------------------------------
// K3: logits = h1_new @ w_out^T + b_out (BM=32, N=64, K=512); log_softmax +
// argmax fused. 256 blocks x 128 threads. A: LDS dbuf; B: reg-frags from
// frag-layout wout (L2-broadcast). Per iter: 1 stage + 4 B-loads ->
// vmcnt(5) (iter 0: vmcnt(0)).
// ---------------------------------------------------------------------------
__global__ __launch_bounds__(128) void out_mfma(
    const __bf16* __restrict__ h1b, const __bf16* __restrict__ woutf,
    const float* __restrict__ bout, float* __restrict__ y, int* __restrict__ p)
{
    __shared__ __bf16 As[2][32 * 32];   // 2 x 2 KB

    const int tid  = threadIdx.x;
    const int lane = tid & 63;
    const int w    = tid >> 6;            // 0..1
    const int m0   = blockIdx.x * 32;
    const int u    = lane & 15, q = lane >> 4;
    const int k0   = (q ^ ((u >> 1) & 3)) * 8;
    const int scol = ((tid & 3) ^ ((tid >> 3) & 3)) * 8;
    const int wo   = w * 512;

    f32x4 acc[4] = {};
    bf16x8 bfr[2][4];

    const __bf16* Ap = h1b + (size_t)(m0 + (tid >> 2)) * HID + scol;
    const __bf16* Bf = woutf + lane * 8;
    #define BFRW(nf, kt) (*(const bf16x8*)(Bf + (size_t)((nf) * 16 + (kt)) * 512))

    GLOAD_LDS16(Ap, &As[0][wo]); Ap += 32;
    #pragma unroll
    for (int nf = 0; nf < 4; ++nf) bfr[0][nf] = BFRW(nf, 0);
    PROLOGUE_FENCE();

    #pragma unroll
    for (int kt = 0; kt < 16; ++kt) {
        const int cur = kt & 1;
        if (kt < 15) {
            GLOAD_LDS16(Ap, &As[cur ^ 1][wo]); Ap += 32;
            #pragma unroll
            for (int nf = 0; nf < 4; ++nf) bfr[cur ^ 1][nf] = BFRW(nf, kt + 1);
            if (kt == 0) asm volatile("s_waitcnt vmcnt(0)" ::: "memory");
            else         asm volatile("s_waitcnt vmcnt(5)" ::: "memory");
        } else {
            asm volatile("s_waitcnt vmcnt(0)" ::: "memory");
        }
        __builtin_amdgcn_s_barrier();

        const bf16x8 af = *(const bf16x8*)&As[cur][(w * 16 + u) * 32 + k0];
        #pragma unroll
        for (int nf = 0; nf < 4; ++nf)
            acc[nf] = __builtin_amdgcn_mfma_f32_16x16x32_bf16(
                af, bfr[cur][nf], acc[nf], 0, 0, 0);

        asm volatile("s_waitcnt lgkmcnt(0)" ::: "memory");
        __builtin_amdgcn_s_barrier();
    }

    #pragma unroll
    for (int r = 0; r < 4; ++r) {
        const int row = m0 + w * 16 + (q << 2) + r;
        float l[4];
        #pragma unroll
        for (int nf = 0; nf < 4; ++nf) l[nf] = acc[nf][r] + bout[nf * 16 + u];

        float mv = l[0]; int mi = u;
        #pragma unroll
        for (int nf = 1; nf < 4; ++nf)
            if (l[nf] > mv) { mv = l[nf]; mi = nf * 16 + u; }
        #pragma unroll
        for (int off = 1; off <= 8; off <<= 1) {
            const float ov = __shfl_xor(mv, off, 64);
            const int   oi = __shfl_xor(mi, off, 64);
            if (ov > mv || (ov == mv && oi < mi)) { mv = ov; mi = oi; }
        }
        float se = 0.f;
        #pragma unroll
        for (int nf = 0; nf < 4; ++nf) se += __expf(l[nf] - mv);
        #pragma unroll
        for (int off = 1; off <= 8; off <<= 1) se += __shfl_xor(se, off, 64);
        const float lse = logf(se);

        #pragma unroll
        for (int nf = 0; nf < 4; ++nf)
            y[(size_t)row * ATOM + nf * 16 + u] = l[nf] - mv - lse;
        if (u == 0) p[row] = mi;
    }
}

// ---------------------------------------------------------------------------
// Init GEMM (enc -> h): 128x128 tile, LDS-staged, tanh epilogue split h0|h1.
// Runs once; left in the simple 2-barrier form.
// ---------------------------------------------------------------------------
__global__ __launch_bounds__(256) void gemm_init(
    const __bf16* __restrict__ A, const __bf16* __restrict__ B,
    int N, int K, const float* __restrict__ bias,
    float* __restrict__ H0f, __bf16* __restrict__ H0b,
    float* __restrict__ H1f, __bf16* __restrict__ H1b)
{
    __shared__ __bf16 As[128 * 32];
    __shared__ __bf16 Bs[128 * 32];

    const int tid  = threadIdx.x;
    const int lane = tid & 63;
    const int w    = tid >> 6;
    const int wm   = w >> 1, wn = w & 1;
    const int m0   = blockIdx.x * 128;
    const int n0   = blockIdx.y * 128;

    f32x4 acc[4][4] = {};

    const int i0 = w * 64 + lane;
    const int i1 = i0 + 256;
    const __bf16* Ap0 = A + (size_t)(m0 + (i0 >> 2)) * K + (i0 & 3) * 8;
    const __bf16* Ap1 = A + (size_t)(m0 + (i1 >> 2)) * K + (i1 & 3) * 8;
    const __bf16* Bp0 = B + (size_t)(n0 + (i0 >> 2)) * K + (i0 & 3) * 8;
    const __bf16* Bp1 = B + (size_t)(n0 + (i1 >> 2)) * K + (i1 & 3) * 8;
    __bf16* As0 = As + w * 512;
    __bf16* As1 = As + 2048 + w * 512;
    __bf16* Bs0 = Bs + w * 512;
    __bf16* Bs1 = Bs + 2048 + w * 512;

    const int mrow = wm * 64 + (lane & 15);
    const int nrow = wn * 64 + (lane & 15);
    const int koff = (lane >> 4) * 8;

    for (int kt = 0; kt < K / 32; ++kt) {
        __syncthreads();
        GLOAD_LDS16(Ap0, As0);
        GLOAD_LDS16(Ap1, As1);
        GLOAD_LDS16(Bp0, Bs0);
        GLOAD_LDS16(Bp1, Bs1);
        Ap0 += 32; Ap1 += 32; Bp0 += 32; Bp1 += 32;
        __syncthreads();

        bf16x8 af[4], bfr[4];
        #pragma unroll
        for (int f = 0; f < 4; ++f) {
            af[f]  = *(const bf16x8*)&As[(mrow + f * 16) * 32 + koff];
            bfr[f] = *(const bf16x8*)&Bs[(nrow + f * 16) * 32 + koff];
        }
        #pragma unroll
        for (int mf = 0; mf < 4; ++mf)
            #pragma unroll
            for (int nf = 0; nf < 4; ++nf)
                acc[mf][nf] = __builtin_amdgcn_mfma_f32_16x16x32_bf16(
                    af[mf], bfr[nf], acc[mf][nf], 0, 0, 0);
    }

    const int colb = n0 + wn * 64 + (lane & 15);
    const int rowb = m0 + wm * 64 + ((lane >> 4) << 2);
    #pragma unroll
    for (int mf = 0; mf < 4; ++mf)
        #pragma unroll
        for (int nf = 0; nf < 4; ++nf) {
            const int col = colb + nf * 16;
            #pragma unroll
            for (int r = 0; r < 4; ++r) {
                const int row = rowb + mf * 16 + r;
                const float v = tanhf(acc[mf][nf][r] + bias[col]);
                if (col < HID) {
                    H0f[(size_t)row * HID + col] = v;
                    H0b[(size_t)row * HID + col] = (__bf16)v;
                } else {
                    H1f[(size_t)row * HID + col - HID] = v;
                    H1b[(size_t)row * HID + col - HID] = (__bf16)v;
                }
            }
        }
}

// ---------------------------------------------------------------------------
// prep kernels
// ---------------------------------------------------------------------------
__device__ inline int permQ(int q) {          // permuted q -> original row
    const int t = q / 48, rem = q % 48;
    return (rem / 16) * HID + t * 16 + (rem % 16);
}

// frag-layout offset for elem (r, k) of a [R][512] matrix
__device__ inline size_t fragOff(int r, int k) {
    return (size_t)((r >> 4) * 16 + (k >> 5)) * 512 +
           ((k >> 3) & 3) * 128 + (r & 15) * 8 + (k & 7);
}

__global__ __launch_bounds__(256) void f2b(const float* __restrict__ s,
                                           __bf16* __restrict__ d, int n)
{
    const int i = (blockIdx.x * 256 + threadIdx.x) * 4;
    if (i + 3 < n) {
        const float4 v = *(const float4*)(s + i);
        bf16x4 o = { (__bf16)v.x, (__bf16)v.y, (__bf16)v.z, (__bf16)v.w };
        *(bf16x4*)(d + i) = o;
    }
}

// gate-perm + frag layout for the three 1536x512 GRU weights
__global__ __launch_bounds__(256) void f2bpf(const float* __restrict__ s,
                                             __bf16* __restrict__ d)
{
    const int idx = blockIdx.x * 256 + threadIdx.x;   // 1536*128
    const int q = idx >> 7, k4 = (idx & 127) << 2;
    const int o = permQ(q);
    const float4 v = *(const float4*)(s + (size_t)o * HID + k4);
    bf16x4 ov = { (__bf16)v.x, (__bf16)v.y, (__bf16)v.z, (__bf16)v.w };
    *(bf16x4*)(d + fragOff(q, k4)) = ov;
}

// frag layout for wout (64 x 512)
__global__ __launch_bounds__(256) void f2bf(const float* __restrict__ s,
                                            __bf16* __restrict__ d)
{
    const int idx = blockIdx.x * 256 + threadIdx.x;   // 64*128
    if (idx >= ATOM * 128) return;
    const int r = idx >> 7, k4 = (idx & 127) << 2;
    const float4 v = *(const float4*)(s + (size_t)r * HID + k4);
    bf16x4 ov = { (__bf16)v.x, (__bf16)v.y, (__bf16)v.z, (__bf16)v.w };
    *(bf16x4*)(d + fragOff(r, k4)) = ov;
}

__global__ __launch_bounds__(256) void bperm(const float* __restrict__ s,
                                             float* __restrict__ d)
{
    const int q = blockIdx.x * 256 + threadIdx.x;
    if (q < GATE3) d[q] = s[permQ(q)];
}

__global__ __launch_bounds__(256) void g0pk(const float* __restrict__ emb,
                                            const float* __restrict__ wih0,
                                            const float* __restrict__ bih0,
                                            float* __restrict__ G0p)
{
    const int i = blockIdx.x * 256 + threadIdx.x;   // 64*1536
    if (i >= ATOM * GATE3) return;
    const int a = i / GATE3, q = i % GATE3;
    const int o = permQ(q);
    float s = bih0[o];
    for (int k = 0; k < 50; ++k) s += emb[a * 50 + k] * wih0[o * 50 + k];
    G0p[i] = s;
}

__global__ __launch_bounds__(256) void initp(int* __restrict__ p)
{
    const int i = blockIdx.x * 256 + threadIdx.x;
    if (i < B_ROWS) p[i] = 1;   // SOS
}

// ---------------------------------------------------------------------------
extern "C" void kernel_launch(void* const* d_in, const int* in_sizes, int n_in,
                              void* d_out, int out_size, void* d_ws, size_t ws_size,
                              hipStream_t stream)
{
    (void)in_sizes; (void)n_in; (void)out_size; (void)ws_size;
    const float* enc   = (const float*)d_in[0];
    const float* emb   = (const float*)d_in[1];
    const float* w_h0  = (const float*)d_in[2];
    const float* b_h0  = (const float*)d_in[3];
    const float* w_ih0 = (const float*)d_in[4];
    const float* w_hh0 = (const float*)d_in[5];
    const float* b_ih0 = (const float*)d_in[6];
    const float* b_hh0 = (const float*)d_in[7];
    const float* w_ih1 = (const float*)d_in[8];
    const float* w_hh1 = (const float*)d_in[9];
    const float* b_ih1 = (const float*)d_in[10];
    const float* b_hh1 = (const float*)d_in[11];
    const float* w_out = (const float*)d_in[12];
    const float* b_out = (const float*)d_in[13];
    float* out = (float*)d_out;

    char* ws = (char*)d_ws;
    size_t off = 0;
    auto alloc = [&](size_t bytes) -> void* {
        void* pp = ws + off;
        off = (off + bytes + 255) & ~(size_t)255;
        return pp;
    };
    __bf16* whh0f = (__bf16*)alloc((size_t)GATE3 * HID * 2);
    __bf16* wih1f = (__bf16*)alloc((size_t)GATE3 * HID * 2);
    __bf16* whh1f = (__bf16*)alloc((size_t)GATE3 * HID * 2);
    __bf16* woutf = (__bf16*)alloc((size_t)ATOM * HID * 2);
    float*  G0p   = (float*) alloc((size_t)ATOM * GATE3 * 4);
    float*  bhh0p = (float*) alloc(GATE3 * 4);
    float*  bih1p = (float*) alloc(GATE3 * 4);
    float*  bhh1p = (float*) alloc(GATE3 * 4);
    float*  h0f[2]; __bf16* h0b[2]; float* h1f[2]; __bf16* h1b[2];
    for (int i = 0; i < 2; ++i) {
        h0f[i] = (float*) alloc((size_t)B_ROWS * HID * 4);
        h0b[i] = (__bf16*)alloc((size_t)B_ROWS * HID * 2);
        h1f[i] = (float*) alloc((size_t)B_ROWS * HID * 4);
        h1b[i] = (__bf16*)alloc((size_t)B_ROWS * HID * 2);
    }
    int* p = (int*)alloc((size_t)B_ROWS * 4);
    __bf16* enc_b = (__bf16*)alloc((size_t)B_ROWS * 1024 * 2);
    __bf16* wh0b  = (__bf16*)alloc((size_t)1024 * 1024 * 2);

    // ---- prep ----
    f2b  <<<8192, 256, 0, stream>>>(enc,  enc_b, B_ROWS * 1024);
    f2b  <<<1024, 256, 0, stream>>>(w_h0, wh0b,  1024 * 1024);
    f2bf <<<32,   256, 0, stream>>>(w_out, woutf);
    f2bpf<<<768,  256, 0, stream>>>(w_hh0, whh0f);
    f2bpf<<<768,  256, 0, stream>>>(w_ih1, wih1f);
    f2bpf<<<768,  256, 0, stream>>>(w_hh1, whh1f);
    bperm<<<6, 256, 0, stream>>>(b_hh0, bhh0p);
    bperm<<<6, 256, 0, stream>>>(b_ih1, bih1p);
    bperm<<<6, 256, 0, stream>>>(b_hh1, bhh1p);
    g0pk<<<384, 256, 0, stream>>>(emb, w_ih0, b_ih0, G0p);
    initp<<<32, 256, 0, stream>>>(p);

    gemm_init<<<dim3(B_ROWS / 128, 1024 / 128), 256, 0, stream>>>(
        enc_b, wh0b, 1024, 1024, b_h0, h0f[0], h0b[0], h1f[0], h1b[0]);

    // ---- 49 decode steps: 3 launches each ----
    const dim3 gGrid(B_ROWS / 64, GATE3 / 192);   // m-tile fastest (XCD locality)
    for (int step = 0; step < NSTEP; ++step) {
        const int cur = step & 1, nxt = cur ^ 1;
        gru0_step<<<gGrid, 256, 0, stream>>>(
            h0b[cur], whh0f, G0p, p, bhh0p, h0f[cur], h0f[nxt], h0b[nxt]);
        gru1_fused<<<gGrid, 256, 0, stream>>>(
            h0b[nxt], wih1f, h1b[cur], whh1f, bih1p, bhh1p,
            h1f[cur], h1f[nxt], h1b[nxt]);
        out_mfma<<<B_ROWS / 32, 128, 0, stream>>>(
            h1b[nxt], woutf, b_out, out + (size_t)step * B_ROWS * ATOM, p);
    }
}